// Round 7
// baseline (191.919 us; speedup 1.0000x reference)
//
#include <hip/hip_runtime.h>

#define B 8
#define C 512
#define D 2048     // spatial positions
#define L 2049     // D+1
#define NH 8
#define CH 64
#define NLT 32     // l-tiles of 64 in the fused pass
#define TLD 513    // LDS tile leading dim (odd stride -> conflict-free)

__device__ __forceinline__ float wave_sum(float v) {
  #pragma unroll
  for (int off = 32; off; off >>= 1) v += __shfl_down(v, off);
  return v;
}
__device__ __forceinline__ float wave_max(float v) {
  #pragma unroll
  for (int off = 32; off; off >>= 1) v = fmaxf(v, __shfl_down(v, off));
  return v;
}
// wave-uniform broadcast via v_readlane (SGPR result, no DS-pipe traffic).
// l must be compile-time constant (use inside fully-unrolled loops).
__device__ __forceinline__ float lane_bcast(float v, int l) {
  return __uint_as_float(__builtin_amdgcn_readlane(__float_as_uint(v), l));
}

// ---- K1: mps[b,c] = mean_l x[b,c,l] + pos[c,0]. One block per (b,c) row. ----
__global__ void __launch_bounds__(256) k_mean(const float* __restrict__ x,
                                              const float* __restrict__ pos,
                                              float* __restrict__ mps_g) {
  int row = blockIdx.x;  // b*C + c
  const float4* xr = reinterpret_cast<const float4*>(x + (size_t)row * D);
  float s = 0.f;
  #pragma unroll
  for (int i = 0; i < 2; ++i) {
    float4 v = xr[threadIdx.x + i * 256];
    s += (v.x + v.y) + (v.z + v.w);
  }
  __shared__ float red[4];
  s = wave_sum(s);
  if ((threadIdx.x & 63) == 0) red[threadIdx.x >> 6] = s;
  __syncthreads();
  if (threadIdx.x == 0)
    mps_g[row] = (red[0] + red[1] + red[2] + red[3]) * (1.0f / D)
               + pos[(size_t)(row & (C - 1)) * L];
}

// ---- K2: q0 -> u[b,h,:] -> logit0[b,h]. One block per (b,h). ----
// (k-bias term is constant over l -> softmax-invariant -> dropped.)
__global__ void __launch_bounds__(256) k_qu(const float* __restrict__ wqkv,
                                            const float* __restrict__ bqkv,
                                            const float* __restrict__ mps_g,
                                            float* __restrict__ u,
                                            float* __restrict__ logit0) {
  int bh = blockIdx.x, b = bh >> 3, h = bh & 7;
  int tid = threadIdx.x, wid = tid >> 6, lane = tid & 63;
  __shared__ float mps[C];
  __shared__ float q0s[CH];
  __shared__ float us[C];
  __shared__ float red[4];
  for (int c = tid; c < C; c += 256) mps[c] = mps_g[b * C + c];
  __syncthreads();
  for (int j = wid; j < CH; j += 4) {
    const float* wr = wqkv + (size_t)(h * CH + j) * C;
    float acc = 0.f;
    #pragma unroll
    for (int k = 0; k < 8; ++k) acc += wr[lane + k * 64] * mps[lane + k * 64];
    acc = wave_sum(acc);
    if (lane == 0) q0s[j] = acc + bqkv[h * CH + j];
  }
  __syncthreads();
  float a0 = 0.f, a1 = 0.f;
  #pragma unroll 4
  for (int j = 0; j < CH; ++j) {
    float qv = q0s[j];
    const float* wkr = wqkv + (size_t)(C + h * CH + j) * C;
    a0 += qv * wkr[tid];
    a1 += qv * wkr[tid + 256];
  }
  a0 *= 0.125f; a1 *= 0.125f;   // scale^2 = 1/sqrt(64)
  us[tid] = a0; us[tid + 256] = a1;
  u[(size_t)bh * C + tid] = a0;
  u[(size_t)bh * C + tid + 256] = a1;
  __syncthreads();
  float p = us[tid] * mps[tid] + us[tid + 256] * mps[tid + 256];
  p = wave_sum(p);
  if (lane == 0) red[wid] = p;
  __syncthreads();
  if (tid == 0) logit0[bh] = red[0] + red[1] + red[2] + red[3];
}

// ---- K3: fused logits + local softmax + xbar partials. grid (NLT, B), 512 thr.
// Phase A: wave<->64c chunk, lane<->l. Loads BATCHED into v_arr[64] (two pure
// unrolled load loops -> 64 loads in flight) before ds_write+fmac consume them.
// u broadcast via v_readlane (compile-time idx). Phase B: thread<->c, tile
// reads batched 32-at-a-time, e broadcast via v_readlane. ----
__global__ void __launch_bounds__(512, 2) k_fused_lx(
    const float* __restrict__ x, const float* __restrict__ pos,
    const float* __restrict__ u_g,
    float* __restrict__ xpart, float* __restrict__ mpart, float* __restrict__ spart) {
  __shared__ float tile[64][TLD];     // 131328 B
  __shared__ float rlds[8][NH][64];   // 16384 B
  __shared__ float e_t[64][9];        // 2304 B   (~150 KB total, 1 block/CU)
  int lt = blockIdx.x, b = blockIdx.y;
  int tid = threadIdx.x, wid = tid >> 6, lane = tid & 63;
  int cg = wid * 64;
  int col = lt * 64 + lane;           // x column; actual l = col+1

  float ureg[NH];
  #pragma unroll
  for (int h = 0; h < NH; ++h) ureg[h] = u_g[(size_t)(b * NH + h) * C + cg + lane];

  const float* xp = x + ((size_t)(b * C + cg)) * D + col;
  const float* pp = pos + (size_t)cg * L + col + 1;

  // batched loads: 64 independent x loads, then 64 pos loads
  float v_arr[64];
  #pragma unroll
  for (int cc = 0; cc < 64; ++cc) v_arr[cc] = xp[(size_t)cc * D];
  #pragma unroll
  for (int cc = 0; cc < 64; ++cc) v_arr[cc] += pp[(size_t)cc * L];

  float acc[NH];
  #pragma unroll
  for (int h = 0; h < NH; ++h) acc[h] = 0.f;
  #pragma unroll
  for (int cc = 0; cc < 64; ++cc) {
    tile[lane][cg + cc] = v_arr[cc];
    #pragma unroll
    for (int h = 0; h < NH; ++h) acc[h] += lane_bcast(ureg[h], cc) * v_arr[cc];
  }
  #pragma unroll
  for (int h = 0; h < NH; ++h) rlds[wid][h][lane] = acc[h];
  __syncthreads();

  {  // wave wid finishes head h = wid: reduce over waves, local softmax
    int h = wid;
    float lg = 0.f;
    #pragma unroll
    for (int w = 0; w < 8; ++w) lg += rlds[w][h][lane];
    float m = wave_max(lg);
    m = lane_bcast(m, 0);
    float e = __expf(lg - m);
    float s = wave_sum(e);
    e_t[lane][h] = e;               // transposed: e_t[l][h]
    if (lane == 0) {
      mpart[(b * NH + h) * NLT + lt] = m;
      spart[(b * NH + h) * NLT + lt] = s;
    }
  }
  __syncthreads();

  // Phase B: thread <-> c; tile reads batched, e via registers + readlane.
  float epre[NH];
  #pragma unroll
  for (int h = 0; h < NH; ++h) epre[h] = e_t[lane][h];
  float a2[NH];
  #pragma unroll
  for (int h = 0; h < NH; ++h) a2[h] = 0.f;
  #pragma unroll
  for (int half = 0; half < 2; ++half) {
    float xv[32];
    #pragma unroll
    for (int i = 0; i < 32; ++i) xv[i] = tile[half * 32 + i][tid];
    #pragma unroll
    for (int i = 0; i < 32; ++i) {
      #pragma unroll
      for (int h = 0; h < NH; ++h)
        a2[h] += lane_bcast(epre[h], half * 32 + i) * xv[i];
    }
  }
  #pragma unroll
  for (int h = 0; h < NH; ++h)
    xpart[(((size_t)b * NLT + lt) * NH + h) * C + tid] = a2[h];
}

// ---- K4: tail. One block per b: combine partials -> xbar[8][512] (LDS),
//      a0 = W_v.xbar + b_v (LDS), out = W_c.a0 + b_c. ----
__global__ void __launch_bounds__(512) k_tail(
    const float* __restrict__ xpart, const float* __restrict__ mpart,
    const float* __restrict__ spart, const float* __restrict__ logit0,
    const float* __restrict__ mps_g,
    const float* __restrict__ wqkv, const float* __restrict__ bqkv,
    const float* __restrict__ wc, const float* __restrict__ bc,
    float* __restrict__ out) {
  int b = blockIdx.x;
  int tid = threadIdx.x, wid = tid >> 6, lane = tid & 63;
  __shared__ float xb[NH][C];   // 16 KB
  __shared__ float a0s[C];      // 2 KB

  // step 1: wave wid = head h. Combine factors in lane regs, then xbar row.
  {
    int h = wid, bh = b * NH + h;
    float lg0 = logit0[bh];
    float mt = (lane < NLT) ? mpart[bh * NLT + lane] : -3.0e38f;
    float M = fmaxf(lane_bcast(wave_max(mt), 0), lg0);
    float rr = (lane < NLT) ? __expf(mt - M) : 0.f;
    float st = (lane < NLT) ? spart[bh * NLT + lane] * rr : 0.f;
    float S = lane_bcast(wave_sum(st), 0) + __expf(lg0 - M);
    float Sinv = 1.0f / S;
    float e0 = __expf(lg0 - M);
    #pragma unroll
    for (int kb = 0; kb < 8; ++kb) {
      int c = kb * 64 + lane;
      float acc = 0.f;
      #pragma unroll
      for (int t = 0; t < NLT; ++t)
        acc += xpart[(((size_t)b * NLT + t) * NH + h) * C + c] * lane_bcast(rr, t);
      xb[h][c] = (acc + e0 * mps_g[b * C + c]) * Sinv;
    }
  }
  __syncthreads();

  // step 2: a0[o] for o in [wid*64, wid*64+64); h(o) = wid.
  {
    float xr[8];
    #pragma unroll
    for (int k = 0; k < 8; ++k) xr[k] = xb[wid][k * 64 + lane];
    for (int j = 0; j < 64; ++j) {
      int o = wid * 64 + j;
      const float* wr = wqkv + (size_t)(2 * C + o) * C;
      float d = 0.f;
      #pragma unroll
      for (int k = 0; k < 8; ++k) d += wr[k * 64 + lane] * xr[k];
      d = wave_sum(d);
      if (lane == 0) a0s[o] = d + bqkv[2 * C + o];
    }
  }
  __syncthreads();

  // step 3: out[o] for o in [wid*64, wid*64+64)
  {
    float ar[8];
    #pragma unroll
    for (int k = 0; k < 8; ++k) ar[k] = a0s[k * 64 + lane];
    for (int j = 0; j < 64; ++j) {
      int o = wid * 64 + j;
      const float* wr = wc + (size_t)o * C;
      float d = 0.f;
      #pragma unroll
      for (int k = 0; k < 8; ++k) d += wr[k * 64 + lane] * ar[k];
      d = wave_sum(d);
      if (lane == 0) out[b * C + o] = d + bc[o];
    }
  }
}

extern "C" void kernel_launch(void* const* d_in, const int* in_sizes, int n_in,
                              void* d_out, int out_size, void* d_ws, size_t ws_size,
                              hipStream_t stream) {
  const float* x    = (const float*)d_in[0];
  const float* pos  = (const float*)d_in[1];
  const float* wqkv = (const float*)d_in[2];
  const float* bqkv = (const float*)d_in[3];
  const float* wc   = (const float*)d_in[4];
  const float* bc   = (const float*)d_in[5];
  float* out = (float*)d_out;
  float* ws  = (float*)d_ws;

  float* mps_g  = ws;               // 4096
  float* u      = ws + 4096;        // 32768
  float* logit0 = ws + 36864;       // 64
  float* mpart  = ws + 36928;       // 2048
  float* spart  = ws + 38976;       // 2048
  float* xpart  = ws + 41024;       // 8*32*8*512 = 1048576  (total ~4.2 MB)

  hipLaunchKernelGGL(k_mean,     dim3(B * C),  dim3(256), 0, stream, x, pos, mps_g);
  hipLaunchKernelGGL(k_qu,       dim3(B * NH), dim3(256), 0, stream, wqkv, bqkv, mps_g, u, logit0);
  hipLaunchKernelGGL(k_fused_lx, dim3(NLT, B), dim3(512), 0, stream, x, pos, u, xpart, mpart, spart);
  hipLaunchKernelGGL(k_tail,     dim3(B),      dim3(512), 0, stream, xpart, mpart, spart, logit0,
                     mps_g, wqkv, bqkv, wc, bc, out);
}

// Round 8
// 58.764 us; speedup vs baseline: 3.2659x; 3.2659x over previous
//
#include <hip/hip_runtime.h>

#define B 8
#define C 512
#define D 2048     // spatial positions
#define L 2049     // D+1
#define NH 8
#define CH 64
#define NLT 32     // l-tiles of 64 in the fused pass
#define TLD 513    // LDS tile leading dim (odd stride -> conflict-free)

__device__ __forceinline__ float wave_sum(float v) {
  #pragma unroll
  for (int off = 32; off; off >>= 1) v += __shfl_down(v, off);
  return v;
}
__device__ __forceinline__ float wave_max(float v) {
  #pragma unroll
  for (int off = 32; off; off >>= 1) v = fmaxf(v, __shfl_down(v, off));
  return v;
}
// wave-uniform broadcast via v_readlane (SGPR result, no DS-pipe traffic).
// l must be compile-time constant (use inside fully-unrolled loops).
__device__ __forceinline__ float lane_bcast(float v, int l) {
  return __uint_as_float(__builtin_amdgcn_readlane(__float_as_uint(v), l));
}

// ---- K1: mps[b,c] = mean_l x[b,c,l] + pos[c,0]. One block per (b,c) row. ----
__global__ void __launch_bounds__(256) k_mean(const float* __restrict__ x,
                                              const float* __restrict__ pos,
                                              float* __restrict__ mps_g) {
  int row = blockIdx.x;  // b*C + c
  const float4* xr = reinterpret_cast<const float4*>(x + (size_t)row * D);
  float s = 0.f;
  #pragma unroll
  for (int i = 0; i < 2; ++i) {
    float4 v = xr[threadIdx.x + i * 256];
    s += (v.x + v.y) + (v.z + v.w);
  }
  __shared__ float red[4];
  s = wave_sum(s);
  if ((threadIdx.x & 63) == 0) red[threadIdx.x >> 6] = s;
  __syncthreads();
  if (threadIdx.x == 0)
    mps_g[row] = (red[0] + red[1] + red[2] + red[3]) * (1.0f / D)
               + pos[(size_t)(row & (C - 1)) * L];
}

// ---- K2: q0 -> u[b,h,:] -> logit0[b,h]. One block per (b,h). ----
// (k-bias term is constant over l -> softmax-invariant -> dropped.)
__global__ void __launch_bounds__(256) k_qu(const float* __restrict__ wqkv,
                                            const float* __restrict__ bqkv,
                                            const float* __restrict__ mps_g,
                                            float* __restrict__ u,
                                            float* __restrict__ logit0) {
  int bh = blockIdx.x, b = bh >> 3, h = bh & 7;
  int tid = threadIdx.x, wid = tid >> 6, lane = tid & 63;
  __shared__ float mps[C];
  __shared__ float q0s[CH];
  __shared__ float us[C];
  __shared__ float red[4];
  for (int c = tid; c < C; c += 256) mps[c] = mps_g[b * C + c];
  __syncthreads();
  for (int j = wid; j < CH; j += 4) {
    const float* wr = wqkv + (size_t)(h * CH + j) * C;
    float acc = 0.f;
    #pragma unroll
    for (int k = 0; k < 8; ++k) acc += wr[lane + k * 64] * mps[lane + k * 64];
    acc = wave_sum(acc);
    if (lane == 0) q0s[j] = acc + bqkv[h * CH + j];
  }
  __syncthreads();
  float a0 = 0.f, a1 = 0.f;
  #pragma unroll 4
  for (int j = 0; j < CH; ++j) {
    float qv = q0s[j];
    const float* wkr = wqkv + (size_t)(C + h * CH + j) * C;
    a0 += qv * wkr[tid];
    a1 += qv * wkr[tid + 256];
  }
  a0 *= 0.125f; a1 *= 0.125f;   // scale^2 = 1/sqrt(64)
  us[tid] = a0; us[tid + 256] = a1;
  u[(size_t)bh * C + tid] = a0;
  u[(size_t)bh * C + tid + 256] = a1;
  __syncthreads();
  float p = us[tid] * mps[tid] + us[tid + 256] * mps[tid + 256];
  p = wave_sum(p);
  if (lane == 0) red[wid] = p;
  __syncthreads();
  if (tid == 0) logit0[bh] = red[0] + red[1] + red[2] + red[3];
}

// ---- K3: fused logits + local softmax + xbar partials. grid (NLT, B), 512 thr.
// Phase A: wave<->64c chunk, lane<->l. Loads BATCHED into v_arr[64] (two pure
// unrolled load loops -> 64 loads in flight) before ds_write+fmac consume them.
// u broadcast via v_readlane (compile-time idx). Phase B: thread<->c, tile
// reads batched 32-at-a-time, e broadcast via v_readlane. ----
__global__ void __launch_bounds__(512, 2) k_fused_lx(
    const float* __restrict__ x, const float* __restrict__ pos,
    const float* __restrict__ u_g,
    float* __restrict__ xpart, float* __restrict__ mpart, float* __restrict__ spart) {
  __shared__ float tile[64][TLD];     // 131328 B
  __shared__ float rlds[8][NH][64];   // 16384 B
  __shared__ float e_t[64][9];        // 2304 B   (~150 KB total, 1 block/CU)
  int lt = blockIdx.x, b = blockIdx.y;
  int tid = threadIdx.x, wid = tid >> 6, lane = tid & 63;
  int cg = wid * 64;
  int col = lt * 64 + lane;           // x column; actual l = col+1

  float ureg[NH];
  #pragma unroll
  for (int h = 0; h < NH; ++h) ureg[h] = u_g[(size_t)(b * NH + h) * C + cg + lane];

  const float* xp = x + ((size_t)(b * C + cg)) * D + col;
  const float* pp = pos + (size_t)cg * L + col + 1;

  // batched loads: 64 independent x loads, then 64 pos loads
  float v_arr[64];
  #pragma unroll
  for (int cc = 0; cc < 64; ++cc) v_arr[cc] = xp[(size_t)cc * D];
  #pragma unroll
  for (int cc = 0; cc < 64; ++cc) v_arr[cc] += pp[(size_t)cc * L];

  float acc[NH];
  #pragma unroll
  for (int h = 0; h < NH; ++h) acc[h] = 0.f;
  #pragma unroll
  for (int cc = 0; cc < 64; ++cc) {
    tile[lane][cg + cc] = v_arr[cc];
    #pragma unroll
    for (int h = 0; h < NH; ++h) acc[h] += lane_bcast(ureg[h], cc) * v_arr[cc];
  }
  #pragma unroll
  for (int h = 0; h < NH; ++h) rlds[wid][h][lane] = acc[h];
  __syncthreads();

  {  // wave wid finishes head h = wid: reduce over waves, local softmax
    int h = wid;
    float lg = 0.f;
    #pragma unroll
    for (int w = 0; w < 8; ++w) lg += rlds[w][h][lane];
    float m = wave_max(lg);
    m = lane_bcast(m, 0);
    float e = __expf(lg - m);
    float s = wave_sum(e);
    e_t[lane][h] = e;               // transposed: e_t[l][h]
    if (lane == 0) {
      mpart[(b * NH + h) * NLT + lt] = m;
      spart[(b * NH + h) * NLT + lt] = s;
    }
  }
  __syncthreads();

  // Phase B: thread <-> c; tile reads batched, e via registers + readlane.
  float epre[NH];
  #pragma unroll
  for (int h = 0; h < NH; ++h) epre[h] = e_t[lane][h];
  float a2[NH];
  #pragma unroll
  for (int h = 0; h < NH; ++h) a2[h] = 0.f;
  #pragma unroll
  for (int half = 0; half < 2; ++half) {
    float xv[32];
    #pragma unroll
    for (int i = 0; i < 32; ++i) xv[i] = tile[half * 32 + i][tid];
    #pragma unroll
    for (int i = 0; i < 32; ++i) {
      #pragma unroll
      for (int h = 0; h < NH; ++h)
        a2[h] += lane_bcast(epre[h], half * 32 + i) * xv[i];
    }
  }
  #pragma unroll
  for (int h = 0; h < NH; ++h)
    xpart[(((size_t)b * NLT + lt) * NH + h) * C + tid] = a2[h];
}

// ---- K4: combine 32 tile-partials + l=0 term, normalize -> xbar row (LDS),
//          then a0 slice for this head. Block = (b,h), 64 blocks. ----
__global__ void __launch_bounds__(512) k_a0(
    const float* __restrict__ xpart, const float* __restrict__ mpart,
    const float* __restrict__ spart, const float* __restrict__ logit0,
    const float* __restrict__ mps_g,
    const float* __restrict__ wqkv, const float* __restrict__ bqkv,
    float* __restrict__ a0v) {
  int bh = blockIdx.x, b = bh >> 3, h = bh & 7;
  int tid = threadIdx.x, wid = tid >> 6, lane = tid & 63;
  __shared__ float row[C];
  float lg0 = logit0[bh];
  // per-wave (redundant) combine factors in lane registers
  float mt = (lane < NLT) ? mpart[bh * NLT + lane] : -3.0e38f;
  float M = fmaxf(lane_bcast(wave_max(mt), 0), lg0);
  float rr = (lane < NLT) ? __expf(mt - M) : 0.f;
  float st = (lane < NLT) ? spart[bh * NLT + lane] * rr : 0.f;
  float S = lane_bcast(wave_sum(st), 0) + __expf(lg0 - M);
  float Sinv = 1.0f / S;
  // xbar[c=tid]
  float acc = 0.f;
  #pragma unroll
  for (int t = 0; t < NLT; ++t)
    acc += xpart[(((size_t)b * NLT + t) * NH + h) * C + tid] * lane_bcast(rr, t);
  acc = (acc + __expf(lg0 - M) * mps_g[b * C + tid]) * Sinv;
  row[tid] = acc;
  __syncthreads();
  // a0[b, h*64+j]: xbar row cached in 8 regs, wave wid handles 8 outputs
  float xr[8];
  #pragma unroll
  for (int k = 0; k < 8; ++k) xr[k] = row[k * 64 + lane];
  #pragma unroll 2
  for (int j = 0; j < 8; ++j) {
    int o = h * CH + wid * 8 + j;
    const float* wr = wqkv + (size_t)(2 * C + o) * C;
    float d = 0.f;
    #pragma unroll
    for (int k = 0; k < 8; ++k) d += wr[k * 64 + lane] * xr[k];
    d = wave_sum(d);
    if (lane == 0) a0v[b * C + o] = d + bqkv[2 * C + o];
  }
}

// ---- K5: out[b,o] = W_c[o,:] . a0[b,:] + b_c[o]. Block = (b, 64-o chunk). ----
__global__ void __launch_bounds__(512) k_out(const float* __restrict__ wc,
                                             const float* __restrict__ bc,
                                             const float* __restrict__ a0v,
                                             float* __restrict__ out) {
  int bid = blockIdx.x, b = bid >> 3, og = (bid & 7) * 64;
  int tid = threadIdx.x, wid = tid >> 6, lane = tid & 63;
  __shared__ float row[C];
  row[tid] = a0v[b * C + tid];
  __syncthreads();
  float ar[8];
  #pragma unroll
  for (int k = 0; k < 8; ++k) ar[k] = row[k * 64 + lane];
  #pragma unroll 2
  for (int j = 0; j < 8; ++j) {
    int o = og + wid * 8 + j;
    const float* wr = wc + (size_t)o * C;
    float d = 0.f;
    #pragma unroll
    for (int k = 0; k < 8; ++k) d += wr[k * 64 + lane] * ar[k];
    d = wave_sum(d);
    if (lane == 0) out[b * C + o] = d + bc[o];
  }
}

extern "C" void kernel_launch(void* const* d_in, const int* in_sizes, int n_in,
                              void* d_out, int out_size, void* d_ws, size_t ws_size,
                              hipStream_t stream) {
  const float* x    = (const float*)d_in[0];
  const float* pos  = (const float*)d_in[1];
  const float* wqkv = (const float*)d_in[2];
  const float* bqkv = (const float*)d_in[3];
  const float* wc   = (const float*)d_in[4];
  const float* bc   = (const float*)d_in[5];
  float* out = (float*)d_out;
  float* ws  = (float*)d_ws;

  float* mps_g  = ws;               // 4096
  float* u      = ws + 4096;        // 32768
  float* logit0 = ws + 36864;       // 64
  float* mpart  = ws + 36928;       // 2048
  float* spart  = ws + 38976;       // 2048
  float* a0v    = ws + 41024;       // 4096
  float* xpart  = ws + 45120;       // 8*32*8*512 = 1048576  (total ~4.2 MB)

  hipLaunchKernelGGL(k_mean,     dim3(B * C),  dim3(256), 0, stream, x, pos, mps_g);
  hipLaunchKernelGGL(k_qu,       dim3(B * NH), dim3(256), 0, stream, wqkv, bqkv, mps_g, u, logit0);
  hipLaunchKernelGGL(k_fused_lx, dim3(NLT, B), dim3(512), 0, stream, x, pos, u, xpart, mpart, spart);
  hipLaunchKernelGGL(k_a0,       dim3(B * NH), dim3(512), 0, stream, xpart, mpart, spart, logit0,
                     mps_g, wqkv, bqkv, a0v);
  hipLaunchKernelGGL(k_out,      dim3(B * NH), dim3(512), 0, stream, wc, bc, a0v, out);
}